// Round 6
// baseline (191.902 us; speedup 1.0000x reference)
//
#include <hip/hip_runtime.h>
#include <hip/hip_bf16.h>
#include <math.h>

#define DEV __device__ __forceinline__

typedef float  floatx4 __attribute__((ext_vector_type(4)));
typedef short  bf16x8  __attribute__((ext_vector_type(8)));
typedef short  bf16x4  __attribute__((ext_vector_type(4)));

typedef __attribute__((address_space(1))) void gvoid;
typedef __attribute__((address_space(3))) void lvoid;

static constexpr int Bc = 2, Tc = 2048, Cc = 1024, Hc = 16, Dc = 64;

DEV void gload16(const void* g, void* l) {
    __builtin_amdgcn_global_load_lds((gvoid*)g, (lvoid*)l, 16, 0, 0);
}

// ---------------------------------------------------------------------------
// Fused prep: fp32->bf16 for x / w_qkv / w_out, plus RoPE cos/sin tables.
// Tables stored TRANSPOSED: cosT[j*2048 + t]  (j = freq index 0..31).
// ---------------------------------------------------------------------------
__global__ void prep_kernel(const float* __restrict__ xf,
                            const float* __restrict__ wqkvf,
                            const float* __restrict__ woutf,
                            __hip_bfloat16* __restrict__ xb,
                            __hip_bfloat16* __restrict__ wqkvb,
                            __hip_bfloat16* __restrict__ woutb,
                            float* __restrict__ cosT, float* __restrict__ sinT) {
    int gb = blockIdx.x;
    if (gb < 8192) {
        const float* src; __hip_bfloat16* dst; int i;
        if (gb < 4096)      { src = xf;    dst = xb;    i = gb * 256 + threadIdx.x; }
        else if (gb < 7168) { src = wqkvf; dst = wqkvb; i = (gb - 4096) * 256 + threadIdx.x; }
        else                { src = woutf; dst = woutb; i = (gb - 7168) * 256 + threadIdx.x; }
        float4 f = ((const float4*)src)[i];
        union { ushort4 u; __hip_bfloat16 h[4]; } pk;
        pk.h[0] = __float2bfloat16(f.x);
        pk.h[1] = __float2bfloat16(f.y);
        pk.h[2] = __float2bfloat16(f.z);
        pk.h[3] = __float2bfloat16(f.w);
        ((ushort4*)dst)[i] = pk.u;
    } else {
        int i = (gb - 8192) * 256 + threadIdx.x;   // 0..65535
        int j = i >> 11, t = i & 2047;             // [j][t] layout, coalesced in t
        float invf = powf(10000.0f, -(float)j / 32.0f);
        float f = (float)t * invf;
        cosT[i] = cosf(f);
        sinT[i] = sinf(f);
    }
}

// ---------------------------------------------------------------------------
// GEMM1 v2: qkv = x @ w_qkv^T. 256x256 tile, BK=64, 8 waves (2M x 4N),
// 8-phase-style schedule (4 phases/K-tile, counted vmcnt(2), T2 pre-swizzled
// staging, T5 setprio around MFMA clusters). 128KB LDS, 1 block/CU.
// Grid (16,12): bn tiles 0-3 = q, 4-7 = k, 8-11 = v (clean 256-col sections).
// Per-wave epilogue (128x64 output, exactly one head's d-range):
//   q/k: RoPE (float4 table loads) -> per-wave LDS chunk-XOR transpose ->
//        coalesced uint4 scatter into (B,H,T,D);
//   v:   per-wave LDS transpose -> (B,H,D,T) line-coalesced.
// ---------------------------------------------------------------------------
__global__ __launch_bounds__(512, 1) void gemm_qkv(
    const __hip_bfloat16* __restrict__ A,   // M x K
    const __hip_bfloat16* __restrict__ Bm,  // N x K
    __hip_bfloat16* __restrict__ qb,
    __hip_bfloat16* __restrict__ kb,
    __hip_bfloat16* __restrict__ vb,        // transposed planes [bh][d][t]
    const float* __restrict__ cosT,
    const float* __restrict__ sinT,
    int K)
{
    __shared__ __align__(16) __hip_bfloat16 SA[2 * 256 * 64];   // A dbuf (64KB)
    __shared__ __align__(16) __hip_bfloat16 SB[2 * 256 * 64];   // B dbuf (64KB)

    const int tid  = threadIdx.x;
    const int lane = tid & 63, wave = tid >> 6;
    const int quad = lane >> 4, cidx = lane & 15;
    const int wm = wave >> 2, wn = wave & 3;           // 2M x 4N waves
    const int bm = blockIdx.x * 256, bn = blockIdx.y * 256;
    const int NT = K >> 6;                             // 16 K-tiles

    floatx4 acc[8][4] = {};

    // ---- prologue: stage K-tile 0 (A 4 loads + B 4 loads) into buf 0 ----
#pragma unroll
    for (int j = 0; j < 4; ++j) {
        int c = tid + j * 512;                         // 0..2047 chunks
        int r = c >> 3, cg = (c & 7) ^ (r & 7);
        gload16(A  + (size_t)(bm + r) * K + cg * 8, SA + c * 8);
    }
#pragma unroll
    for (int j = 0; j < 4; ++j) {
        int c = tid + j * 512;
        int r = c >> 3, cg = (c & 7) ^ (r & 7);
        gload16(Bm + (size_t)(bn + r) * K + cg * 8, SB + c * 8);
    }

    for (int t = 0; t < NT; ++t) {
        const int p = t & 1;
        const __hip_bfloat16* Ab = SA + p * (256 * 64);
        const __hip_bfloat16* Bb = SB + p * (256 * 64);
        __hip_bfloat16* An = SA + (p ^ 1) * (256 * 64);
        __hip_bfloat16* Bn = SB + (p ^ 1) * (256 * 64);
        const int k1 = (t + 1) * 64;
        const bool more = (t < NT - 1);

        bf16x8 bfr[4][2];    // [nt][ks] — held for the whole K-tile
        bf16x8 afr[2][2];    // [msub][ks] — per phase

        // ================= phase 0 =================
        if (more) {
            // stage A-half0 of tile t+1 (2 loads)
#pragma unroll
            for (int j = 0; j < 2; ++j) {
                int c = tid + j * 512;                 // 0..1023
                int r = c >> 3, cg = (c & 7) ^ (r & 7);
                gload16(A + (size_t)(bm + r) * K + k1 + cg * 8, An + c * 8);
            }
            asm volatile("s_waitcnt vmcnt(2)" ::: "memory");   // tile t landed
        } else {
            asm volatile("s_waitcnt vmcnt(0)" ::: "memory");
        }
        __builtin_amdgcn_sched_barrier(0);
        __builtin_amdgcn_s_barrier();                  // buf p complete for all

        // ds reads: all 8 B-frags + A-frags m0,m1
#pragma unroll
        for (int nt = 0; nt < 4; ++nt)
#pragma unroll
            for (int ks = 0; ks < 2; ++ks) {
                int r = wn * 64 + nt * 16 + cidx;
                bfr[nt][ks] = *(const bf16x8*)(Bb + (r * 8 + ((ks * 4 + quad) ^ (r & 7))) * 8);
            }
#pragma unroll
        for (int ms = 0; ms < 2; ++ms)
#pragma unroll
            for (int ks = 0; ks < 2; ++ks) {
                int r = wm * 128 + ms * 16 + cidx;
                afr[ms][ks] = *(const bf16x8*)(Ab + (r * 8 + ((ks * 4 + quad) ^ (r & 7))) * 8);
            }
        __builtin_amdgcn_s_setprio(1);
#pragma unroll
        for (int ks = 0; ks < 2; ++ks)
#pragma unroll
            for (int ms = 0; ms < 2; ++ms)
#pragma unroll
                for (int nt = 0; nt < 4; ++nt)
                    acc[ms][nt] = __builtin_amdgcn_mfma_f32_16x16x32_bf16(
                        afr[ms][ks], bfr[nt][ks], acc[ms][nt], 0, 0, 0);
        __builtin_amdgcn_s_setprio(0);
        __builtin_amdgcn_s_barrier();

        // ================= phases 1..3 =================
#pragma unroll
        for (int ph = 1; ph < 4; ++ph) {
            if (more) {
                // ph1: A-half1; ph2: B-half0; ph3: B-half1 (2 loads each)
                const __hip_bfloat16* g = (ph < 2) ? A : Bm;
                const int rowoff = (ph < 2) ? bm : bn;
                __hip_bfloat16* dstb = (ph < 2) ? An : Bn;
                const int hbase = (ph & 1) * 1024;
#pragma unroll
                for (int j = 0; j < 2; ++j) {
                    int c = hbase + tid + j * 512;
                    int r = c >> 3, cg = (c & 7) ^ (r & 7);
                    gload16(g + (size_t)(rowoff + r) * K + k1 + cg * 8, dstb + c * 8);
                }
            }
            // A-frags for m-blocks {2ph, 2ph+1} (data stable; overlaps others' MFMA)
#pragma unroll
            for (int ms = 0; ms < 2; ++ms)
#pragma unroll
                for (int ks = 0; ks < 2; ++ks) {
                    int r = wm * 128 + (ph * 2 + ms) * 16 + cidx;
                    afr[ms][ks] = *(const bf16x8*)(Ab + (r * 8 + ((ks * 4 + quad) ^ (r & 7))) * 8);
                }
            __builtin_amdgcn_s_barrier();
            __builtin_amdgcn_s_setprio(1);
#pragma unroll
            for (int ks = 0; ks < 2; ++ks)
#pragma unroll
                for (int ms = 0; ms < 2; ++ms)
#pragma unroll
                    for (int nt = 0; nt < 4; ++nt)
                        acc[ph * 2 + ms][nt] = __builtin_amdgcn_mfma_f32_16x16x32_bf16(
                            afr[ms][ks], bfr[nt][ks], acc[ph * 2 + ms][nt], 0, 0, 0);
            __builtin_amdgcn_s_setprio(0);
            __builtin_amdgcn_s_barrier();
        }
    }

    // ---- per-wave epilogue: 128x64 output tile, own 16KB LDS slice ----
    __hip_bfloat16* ws = ((wave < 4) ? SA : SB) + (wave & 3) * 8192;
    const int b = bm >> 11;

    if (bn < 2048) {
        // ---- q / k: RoPE -> LDS chunk-XOR transpose -> coalesced scatter ----
        const float SL2E = 0.125f * 1.44269504088896f;  // softmax scale * log2(e)
        const bool isq = (bn < 1024);
        const int h = ((bn & 1023) >> 6) + wn;          // wave's head
#pragma unroll
        for (int nt = 0; nt < 4; ++nt) {
            int n_l = nt * 16 + cidx;                   // = d (wave col 64-aligned)
            int d = n_l, j = d >> 1;
            const float* cp = cosT + j * 2048;
            const float* sp = sinT + j * 2048;
#pragma unroll
            for (int mt = 0; mt < 8; ++mt) {
                int m0 = wm * 128 + mt * 16 + quad * 4;
                int t0 = (bm + m0) & 2047;              // 4 consecutive t, 16B aligned
                float4 c4 = *(const float4*)(cp + t0);
                float4 s4 = *(const float4*)(sp + t0);
#pragma unroll
                for (int reg = 0; reg < 4; ++reg) {
                    float v = acc[mt][nt][reg];
                    float pr = __shfl_xor(v, 1);
                    float cz = ((const float*)&c4)[reg];
                    float sz = ((const float*)&s4)[reg];
                    float o = (d & 1) ? (pr * sz + v * cz) : (v * cz - pr * sz);
                    if (isq) o *= SL2E;
                    int r_l = mt * 16 + quad * 4 + reg; // 0..127 in wave slice
                    ws[r_l * 64 + (((n_l >> 3) ^ (r_l & 7)) * 8) + (n_l & 7)] =
                        __float2bfloat16(o);
                }
            }
        }
        {
            __hip_bfloat16* dst = isq ? qb : kb;
#pragma unroll
            for (int it = 0; it < 16; ++it) {
                int c = lane + it * 64;                 // 0..1023 16B chunks
                int row = c >> 3, cp8 = c & 7;
                int m = bm + wm * 128 + row;
                int tt = m & 2047;
                *(uint4*)(dst + ((size_t)(b * Hc + h) * Tc + tt) * Dc + cp8 * 8) =
                    *(const uint4*)(ws + row * 64 + ((cp8 ^ (row & 7)) * 8));
            }
        }
    } else {
        // ---- v: per-wave LDS transpose -> [bh][d][t] line-coalesced ----
        const int cc0 = (bn - 2048) + wn * 64;
        const int h = cc0 >> 6;
#pragma unroll
        for (int nt = 0; nt < 4; ++nt) {
            int d_l = nt * 16 + cidx;                   // 0..63
#pragma unroll
            for (int mt = 0; mt < 8; ++mt)
#pragma unroll
                for (int reg = 0; reg < 4; ++reg) {
                    int t_l = mt * 16 + quad * 4 + reg; // 0..127
                    ws[d_l * 128 + (((t_l >> 3) ^ (d_l & 15)) * 8) + (t_l & 7)] =
                        __float2bfloat16(acc[mt][nt][reg]);
                }
        }
        {
            int t0 = (bm + wm * 128) & 2047;
#pragma unroll
            for (int it = 0; it < 16; ++it) {
                int c = lane + it * 64;                 // 0..1023 16B chunks
                int row = c >> 4, cp16 = c & 15;        // row = d, 16 chunks of 8 t
                *(uint4*)(vb + ((size_t)(b * Hc + h) * Dc + row) * Tc + t0 + cp16 * 8) =
                    *(const uint4*)(ws + row * 128 + ((cp16 ^ (row & 15)) * 8));
            }
        }
    }
}

// ---------------------------------------------------------------------------
// GEMM2: out = ab @ w_out^T, fp32 store. 64x128 tile (512 blocks = 2/CU).
// (round-1 config — measured good)
// ---------------------------------------------------------------------------
__global__ __launch_bounds__(256, 2) void gemm_out(
    const __hip_bfloat16* __restrict__ A,   // planar [bh][t][d]
    const __hip_bfloat16* __restrict__ Bm,  // 1024 x 1024
    float* __restrict__ Cout)
{
    __shared__ __align__(16) __hip_bfloat16 As[64 * 64];
    __shared__ __align__(16) __hip_bfloat16 Bs[128 * 64];

    const int tid  = threadIdx.x;
    const int lane = tid & 63, wave = tid >> 6;
    const int quad = lane >> 4, cidx = lane & 15;
    const int bm = blockIdx.x * 64, bn = blockIdx.y * 128;
    const int K = 1024;

    floatx4 acc[4][2] = {};

    for (int k0 = 0; k0 < K; k0 += 64) {
        int h = k0 >> 6;
#pragma unroll
        for (int it = 0; it < 2; ++it) {
            int idx = tid + it * 256;        // 0..511
            int r = idx >> 3, cs = idx & 7;
            int cg = cs ^ (r & 7);
            int m = bm + r;
            const __hip_bfloat16* src =
                A + ((size_t)((m >> 11) * 16 + h) * 2048 + (m & 2047)) * 64 + cg * 8;
            gload16(src, As + idx * 8);
        }
#pragma unroll
        for (int it = 0; it < 4; ++it) {
            int idx = tid + it * 256;        // 0..1023
            int r = idx >> 3, cs = idx & 7;
            int cg = cs ^ (r & 7);
            gload16(Bm + (size_t)(bn + r) * K + k0 + cg * 8, Bs + idx * 8);
        }
        __syncthreads();
#pragma unroll
        for (int ks = 0; ks < 2; ++ks) {
            bf16x8 af[4], bf[2];
#pragma unroll
            for (int mt = 0; mt < 4; ++mt) {
                int r = mt * 16 + cidx;
                af[mt] = *(const bf16x8*)(As + (r * 8 + ((ks * 4 + quad) ^ (r & 7))) * 8);
            }
#pragma unroll
            for (int nt = 0; nt < 2; ++nt) {
                int r = wave * 32 + nt * 16 + cidx;
                bf[nt] = *(const bf16x8*)(Bs + (r * 8 + ((ks * 4 + quad) ^ (r & 7))) * 8);
            }
#pragma unroll
            for (int mt = 0; mt < 4; ++mt)
#pragma unroll
                for (int nt = 0; nt < 2; ++nt)
                    acc[mt][nt] = __builtin_amdgcn_mfma_f32_16x16x32_bf16(
                        af[mt], bf[nt], acc[mt][nt], 0, 0, 0);
        }
        __syncthreads();
    }

#pragma unroll
    for (int mt = 0; mt < 4; ++mt)
#pragma unroll
        for (int nt = 0; nt < 2; ++nt) {
            int n = bn + wave * 32 + nt * 16 + cidx;
#pragma unroll
            for (int reg = 0; reg < 4; ++reg) {
                int m = bm + mt * 16 + quad * 4 + reg;
                Cout[(size_t)m * 1024 + n] = acc[mt][nt][reg];
            }
        }
}

// ---------------------------------------------------------------------------
// Causal MFMA flash attention v6: Q-split + 32q/wave A-fragment reuse.
// (unchanged from round 5 — measured good)
// ---------------------------------------------------------------------------
__global__ __launch_bounds__(256, 2) void attn_kernel(
    const __hip_bfloat16* __restrict__ qb,
    const __hip_bfloat16* __restrict__ kb,
    const __hip_bfloat16* __restrict__ vb,   // [bh][d][t]
    __hip_bfloat16* __restrict__ ob)         // planar [bh][t][d]
{
    __shared__ __align__(16) __hip_bfloat16 KB[2 * 128 * 64];  // K dbuf (32KB)
    __shared__ __align__(16) __hip_bfloat16 VB[2 * 64 * 128];  // V^T dbuf (32KB)

    const int tid  = threadIdx.x;
    const int lane = tid & 63, wave = tid >> 6;
    const int quad = lane >> 4, cidx = lane & 15;
    const int id = blockIdx.x;
    const int xcd = id & 7, s = id >> 3;      // s 0..63
    const int bh  = xcd * 4 + (s & 3);        // 4 bh planes per XCD
    const int m   = s >> 2;                   // 0..15
    const int qt  = (m < 8) ? (15 - m) : (m - 8);   // big blocks first
    const int qbase = qt * 128;
    const int ktmax = qt;
    const size_t plane = (size_t)bh * Tc * Dc;
    const __hip_bfloat16* Vp = vb + plane;
    const __hip_bfloat16* Kp = kb + plane;

    __hip_bfloat16* const Qs = KB + 128 * 64;   // Q staged in K buf1
    __hip_bfloat16* const Os = KB;              // O staged in K buf0

    // ---- prologue: stage Q -> Qs, K(0) -> KB[0], V(0) -> VB[0] ----
#pragma unroll
    for (int it = 0; it < 4; ++it) {
        int idx = tid + it * 256;               // 0..1023
        int r = idx >> 3, cg = (idx & 7) ^ (r & 7);
        gload16(qb + plane + (size_t)(qbase + r) * 64 + cg * 8, Qs + idx * 8);
    }
#pragma unroll
    for (int it = 0; it < 4; ++it) {
        int idx = tid + it * 256;
        int r = idx >> 3, cg = (idx & 7) ^ (r & 7);    // r = key row 0..127
        gload16(Kp + (size_t)r * 64 + cg * 8, KB + idx * 8);
    }
#pragma unroll
    for (int it = 0; it < 4; ++it) {
        int idx = tid + it * 256;
        int r = idx >> 4, c = (idx & 15) ^ (r & 15);   // r = d row 0..63
        gload16(Vp + (size_t)r * Tc + c * 8, VB + idx * 8);
    }
    __syncthreads();

    bf16x8 qf[2][2];
#pragma unroll
    for (int qb2 = 0; qb2 < 2; ++qb2)
#pragma unroll
        for (int ks = 0; ks < 2; ++ks) {
            int r = wave * 32 + qb2 * 16 + cidx;
            qf[qb2][ks] = *(const bf16x8*)(Qs + (r * 8 + ((ks * 4 + quad) ^ (r & 7))) * 8);
        }
    __syncthreads();   // qf in regs before kt=0 stages K(1) over Qs

    floatx4 oaccT[2][4] = {};        // [qb2][dt]; row=d, col=q
    floatx4 lpart[2] = {};           // 4 partial lsum chains per q-block
    const int q0 = qbase + wave * 32 + cidx;

    for (int kt = 0; kt <= ktmax; ++kt) {
        const __hip_bfloat16* Kc = KB + (kt & 1) * (128 * 64);
        const __hip_bfloat16* Vc = VB + (kt & 1) * (64 * 128);

        // stage next K/V tile into the other buffer (drains at end barrier)
        if (kt < ktmax) {
            __hip_bfloat16* Kn = KB + ((kt + 1) & 1) * (128 * 64);
            __hip_bfloat16* Vn = VB + ((kt + 1) & 1) * (64 * 128);
#pragma unroll
            for (int it = 0; it < 4; ++it) {
                int idx = tid + it * 256;
                int r = idx >> 3, cg = (idx & 7) ^ (r & 7);
                gload16(Kp + (size_t)((kt + 1) * 128 + r) * 64 + cg * 8, Kn + idx * 8);
            }
#pragma unroll
            for (int it = 0; it < 4; ++it) {
                int idx = tid + it * 256;
                int r = idx >> 4, c = (idx & 15) ^ (r & 15);
                gload16(Vp + (size_t)r * Tc + (kt + 1) * 128 + c * 8, Vn + idx * 8);
            }
        }

        // S^T = K Q^T : 128 keys x 2x16 q; each af read feeds both q-blocks
        floatx4 sacc[2][8] = {};
#pragma unroll
        for (int ks = 0; ks < 2; ++ks)
#pragma unroll
            for (int kb8 = 0; kb8 < 8; ++kb8) {
                int r = kb8 * 16 + cidx;
                bf16x8 af = *(const bf16x8*)(
                    Kc + (r * 8 + ((ks * 4 + quad) ^ (r & 7))) * 8);
                sacc[0][kb8] = __builtin_amdgcn_mfma_f32_16x16x32_bf16(
                    af, qf[0][ks], sacc[0][kb8], 0, 0, 0);
                sacc[1][kb8] = __builtin_amdgcn_mfma_f32_16x16x32_bf16(
                    af, qf[1][ks], sacc[1][kb8], 0, 0, 0);
            }

        // p = 2^s, causal mask on diagonal tile; pf register-direct
        const bool domask = (kt == ktmax);
        bf16x4 pf[2][8];
#pragma unroll
        for (int qb2 = 0; qb2 < 2; ++qb2) {
            const int q = q0 + qb2 * 16;
#pragma unroll
            for (int kb8 = 0; kb8 < 8; ++kb8)
#pragma unroll
                for (int reg = 0; reg < 4; ++reg) {
                    int key = kt * 128 + kb8 * 16 + quad * 4 + reg;
                    float p = __builtin_amdgcn_exp2f(sacc[qb2][kb8][reg]);
                    if (domask && key > q) p = 0.0f;
                    lpart[qb2][reg] += p;
                    __hip_bfloat16 hb = __float2bfloat16(p);
                    pf[qb2][kb8][reg] = *(const short*)&hb;
                }
        }

        // O^T += V^T P^T : each vtf read feeds both q-blocks
#pragma unroll
        for (int dt = 0; dt < 4; ++dt) {
            int d = dt * 16 + cidx;
#pragma unroll
            for (int c8 = 0; c8 < 8; ++c8) {
                int ch = c8 * 2 + (quad >> 1);
                bf16x4 vtf = *(const bf16x4*)(
                    Vc + (d * 16 + (ch ^ (d & 15))) * 8 + (quad & 1) * 4);
                oaccT[0][dt] = __builtin_amdgcn_mfma_f32_16x16x16bf16_1k(
                    vtf, pf[0][c8], oaccT[0][dt], 0, 0, 0);
                oaccT[1][dt] = __builtin_amdgcn_mfma_f32_16x16x16bf16_1k(
                    vtf, pf[1][c8], oaccT[1][dt], 0, 0, 0);
            }
        }

        __syncthreads();   // stage(kt+1) landed; buf[cur] reads done
    }

    // ---- epilogue: l reduce, normalize, transpose via Os, planar store ----
#pragma unroll
    for (int qb2 = 0; qb2 < 2; ++qb2) {
        float l = lpart[qb2][0] + lpart[qb2][1] + lpart[qb2][2] + lpart[qb2][3];
        l += __shfl_xor(l, 16);
        l += __shfl_xor(l, 32);
        float inv = 1.0f / l;
        int qq = wave * 32 + qb2 * 16 + cidx;
#pragma unroll
        for (int dt = 0; dt < 4; ++dt) {
            bf16x4 o4;
#pragma unroll
            for (int reg = 0; reg < 4; ++reg) {
                __hip_bfloat16 hb = __float2bfloat16(oaccT[qb2][dt][reg] * inv);
                o4[reg] = *(const short*)&hb;
            }
            int g = dt * 4 + quad;
            *(bf16x4*)(Os + qq * 64 + ((g ^ (qq & 12)) * 4)) = o4;
        }
    }
    __syncthreads();
    // cooperative planar store: 128 rows x 128B contiguous
#pragma unroll
    for (int i = 0; i < 4; ++i) {
        int c = tid + i * 256;               // 0..1023 16B chunks
        int row = c >> 3, cp = c & 7;
        *(uint4*)(ob + plane + (size_t)(qbase + row) * 64 + cp * 8) =
            *(const uint4*)(Os + row * 64 + ((cp * 2) ^ (row & 12)) * 4);
    }
}

// ---------------------------------------------------------------------------
extern "C" void kernel_launch(void* const* d_in, const int* in_sizes, int n_in,
                              void* d_out, int out_size, void* d_ws, size_t ws_size,
                              hipStream_t stream) {
    const float* xf = nullptr; const float* wqkvf = nullptr; const float* woutf = nullptr;
    for (int i = 0; i < n_in; ++i) {
        if      (in_sizes[i] == 2 * 2048 * 1024) xf    = (const float*)d_in[i];
        else if (in_sizes[i] == 3 * 1024 * 1024) wqkvf = (const float*)d_in[i];
        else if (in_sizes[i] == 1024 * 1024)     woutf = (const float*)d_in[i];
    }
    float* out = (float*)d_out;   // fp32 output (reference output dtype)

    char* ws = (char*)d_ws;
    const size_t MB = 1024 * 1024;
    __hip_bfloat16* qb    = (__hip_bfloat16*)(ws);
    __hip_bfloat16* kb    = (__hip_bfloat16*)(ws + 8  * MB);
    __hip_bfloat16* vb    = (__hip_bfloat16*)(ws + 16 * MB);   // transposed planes
    __hip_bfloat16* ab    = (__hip_bfloat16*)(ws + 24 * MB);   // planar [bh][t][d]
    float* cosT           = (float*)(ws + 32 * MB);
    float* sinT           = (float*)(ws + 32 * MB + 256 * 1024);
    __hip_bfloat16* xb    = (__hip_bfloat16*)(ws + 33 * MB);
    __hip_bfloat16* wqkvb = (__hip_bfloat16*)(ws + 41 * MB);
    __hip_bfloat16* woutb = (__hip_bfloat16*)(ws + 47 * MB);

    prep_kernel<<<dim3(8448), dim3(256), 0, stream>>>(
        xf, wqkvf, woutf, xb, wqkvb, woutb, cosT, sinT);

    // qkv projection + RoPE (+q pre-scale) + head scatter (v transposed via LDS)
    gemm_qkv<<<dim3(16, 12), dim3(512), 0, stream>>>(
        xb, wqkvb, qb, kb, vb, cosT, sinT, 1024);
    // causal flash attention -> ab planar (B,H,T,D) bf16
    attn_kernel<<<dim3(512), dim3(256), 0, stream>>>(qb, kb, vb, ab);
    // output projection (planar A), fp32 store to d_out
    gemm_out<<<dim3(64, 8), dim3(256), 0, stream>>>(ab, woutb, out);
}

// Round 7
// 162.556 us; speedup vs baseline: 1.1805x; 1.1805x over previous
//
#include <hip/hip_runtime.h>
#include <hip/hip_bf16.h>
#include <math.h>

#define DEV __device__ __forceinline__

typedef float  floatx4 __attribute__((ext_vector_type(4)));
typedef short  bf16x8  __attribute__((ext_vector_type(8)));
typedef short  bf16x4  __attribute__((ext_vector_type(4)));

typedef __attribute__((address_space(1))) void gvoid;
typedef __attribute__((address_space(3))) void lvoid;

static constexpr int Bc = 2, Tc = 2048, Cc = 1024, Hc = 16, Dc = 64;

DEV void gload16(const void* g, void* l) {
    __builtin_amdgcn_global_load_lds((gvoid*)g, (lvoid*)l, 16, 0, 0);
}

// ---------------------------------------------------------------------------
// Fused prep: fp32->bf16 for x / w_qkv / w_out, plus RoPE cos/sin tables.
// Tables stored TRANSPOSED: cosT[j*2048 + t]  (j = freq index 0..31).
// powf -> exp2f (equivalent: 10000^(-j/32) = 2^(-j*log2(1e4)/32)).
// ---------------------------------------------------------------------------
__global__ void prep_kernel(const float* __restrict__ xf,
                            const float* __restrict__ wqkvf,
                            const float* __restrict__ woutf,
                            __hip_bfloat16* __restrict__ xb,
                            __hip_bfloat16* __restrict__ wqkvb,
                            __hip_bfloat16* __restrict__ woutb,
                            float* __restrict__ cosT, float* __restrict__ sinT) {
    int gb = blockIdx.x;
    if (gb < 8192) {
        const float* src; __hip_bfloat16* dst; int i;
        if (gb < 4096)      { src = xf;    dst = xb;    i = gb * 256 + threadIdx.x; }
        else if (gb < 7168) { src = wqkvf; dst = wqkvb; i = (gb - 4096) * 256 + threadIdx.x; }
        else                { src = woutf; dst = woutb; i = (gb - 7168) * 256 + threadIdx.x; }
        float4 f = ((const float4*)src)[i];
        union { ushort4 u; __hip_bfloat16 h[4]; } pk;
        pk.h[0] = __float2bfloat16(f.x);
        pk.h[1] = __float2bfloat16(f.y);
        pk.h[2] = __float2bfloat16(f.z);
        pk.h[3] = __float2bfloat16(f.w);
        ((ushort4*)dst)[i] = pk.u;
    } else {
        int i = (gb - 8192) * 256 + threadIdx.x;   // 0..65535
        int j = i >> 11, t = i & 2047;             // [j][t] layout, coalesced in t
        // 10000^(-j/32) = exp2(-j * log2(10000)/32), log2(1e4)=13.287712379549449
        float invf = exp2f((float)j * -0.4152410118609203f);
        float f = (float)t * invf;
        cosT[i] = cosf(f);
        sinT[i] = sinf(f);
    }
}

// ---------------------------------------------------------------------------
// GEMM1: qkv = x @ w_qkv^T. 128x128 tile, BK=64, m97 pattern + XOR swizzle.
// (round-1 config: 2D grid (32,24) — measured good across rounds 1/4/5.
//  Round-6 8-phase 256^2 port regressed 34->61us, MfmaUtil 15%: prefetch
//  depth 1 phase vs template's 3 half-tiles; reverted.)
// ---------------------------------------------------------------------------
__global__ __launch_bounds__(256, 2) void gemm_qkv(
    const __hip_bfloat16* __restrict__ A,   // M x K
    const __hip_bfloat16* __restrict__ Bm,  // N x K
    __hip_bfloat16* __restrict__ qb,
    __hip_bfloat16* __restrict__ kb,
    __hip_bfloat16* __restrict__ vb,        // transposed planes [bh][d][t]
    const float* __restrict__ cosT,
    const float* __restrict__ sinT,
    int K)
{
    __shared__ __align__(16) __hip_bfloat16 SM[2 * 128 * 64];   // As | Bs (32KB)
    __hip_bfloat16* const As = SM;
    __hip_bfloat16* const Bs = SM + 128 * 64;

    const int tid  = threadIdx.x;
    const int lane = tid & 63, wave = tid >> 6;
    const int quad = lane >> 4, cidx = lane & 15;
    const int wm = wave & 1, wn = wave >> 1;
    const int bm = blockIdx.x * 128, bn = blockIdx.y * 128;

    floatx4 acc[4][4] = {};

    for (int k0 = 0; k0 < K; k0 += 64) {
#pragma unroll
        for (int it = 0; it < 4; ++it) {
            int idx = tid + it * 256;
            int r = idx >> 3, cs = idx & 7;
            int cg = cs ^ (r & 7);
            gload16(A  + (size_t)(bm + r) * K + k0 + cg * 8, As + idx * 8);
            gload16(Bm + (size_t)(bn + r) * K + k0 + cg * 8, Bs + idx * 8);
        }
        __syncthreads();
#pragma unroll
        for (int ks = 0; ks < 2; ++ks) {
            bf16x8 af[4], bf[4];
#pragma unroll
            for (int mt = 0; mt < 4; ++mt) {
                int r = wm * 64 + mt * 16 + cidx;
                af[mt] = *(const bf16x8*)(As + (r * 8 + ((ks * 4 + quad) ^ (r & 7))) * 8);
            }
#pragma unroll
            for (int nt = 0; nt < 4; ++nt) {
                int r = wn * 64 + nt * 16 + cidx;
                bf[nt] = *(const bf16x8*)(Bs + (r * 8 + ((ks * 4 + quad) ^ (r & 7))) * 8);
            }
#pragma unroll
            for (int mt = 0; mt < 4; ++mt)
#pragma unroll
                for (int nt = 0; nt < 4; ++nt)
                    acc[mt][nt] = __builtin_amdgcn_mfma_f32_16x16x32_bf16(
                        af[mt], bf[nt], acc[mt][nt], 0, 0, 0);
        }
        __syncthreads();
    }

    if (bn >= 2048) {
        // ---- v tile: LDS transpose -> [bh][d][t], line-coalesced stores ----
#pragma unroll
        for (int nt = 0; nt < 4; ++nt) {
            int n_l = wn * 64 + nt * 16 + cidx;
#pragma unroll
            for (int mt = 0; mt < 4; ++mt)
#pragma unroll
                for (int reg = 0; reg < 4; ++reg) {
                    int m_l = wm * 64 + mt * 16 + quad * 4 + reg;
                    SM[n_l * 128 + (((m_l >> 3) ^ (n_l & 15)) * 8) + (m_l & 7)] =
                        __float2bfloat16(acc[mt][nt][reg]);
                }
        }
        __syncthreads();
        {
            int b = bm >> 11, t0 = bm & 2047;
            int c = tid & 15;
#pragma unroll
            for (int it = 0; it < 8; ++it) {
                int row = it * 16 + (tid >> 4);     // d dimension
                int cc = (bn - 2048) + row;
                int h = cc >> 6, d = cc & 63;
                *(uint4*)(vb + ((size_t)(b * Hc + h) * Dc + d) * Tc + t0 + c * 8) =
                    *(const uint4*)(SM + row * 128 + ((c ^ (row & 15)) * 8));
            }
        }
    } else {
        // ---- q / k tiles: RoPE in registers, LDS transpose, uint4 scatter ----
        const float SL2E = 0.125f * 1.44269504088896f;  // softmax scale * log2(e)
        const bool isq = (bn < 1024);
#pragma unroll
        for (int nt = 0; nt < 4; ++nt) {
            int n_l = wn * 64 + nt * 16 + cidx;
            int d = n_l & 63, j = d >> 1;
            const float* cp = cosT + j * 2048;
            const float* sp = sinT + j * 2048;
#pragma unroll
            for (int mt = 0; mt < 4; ++mt) {
                int m0 = wm * 64 + mt * 16 + quad * 4;
                int t0 = (bm + m0) & 2047;          // 4 consecutive t, 16B aligned
                float4 c4 = *(const float4*)(cp + t0);
                float4 s4 = *(const float4*)(sp + t0);
#pragma unroll
                for (int reg = 0; reg < 4; ++reg) {
                    float v = acc[mt][nt][reg];
                    float p = __shfl_xor(v, 1);
                    float cz = ((const float*)&c4)[reg];
                    float sz = ((const float*)&s4)[reg];
                    float o = (d & 1) ? (p * sz + v * cz) : (v * cz - p * sz);
                    if (isq) o *= SL2E;
                    int m_l = m0 + reg;
                    SM[m_l * 128 + (((n_l >> 3) ^ (m_l & 15)) * 8) + (n_l & 7)] =
                        __float2bfloat16(o);
                }
            }
        }
        __syncthreads();
        {
            __hip_bfloat16* dst = isq ? qb : kb;
            const int bnl = bn & 1023;
#pragma unroll
            for (int it = 0; it < 8; ++it) {
                int c = it * 256 + tid;             // 0..2047 16B chunks
                int row = c >> 4, s = c & 15;       // row = m_l, s = logical chunk
                int m = bm + row;
                int b = m >> 11, t = m & 2047;
                int h = (bnl >> 6) + (s >> 3);
                int d0 = (s & 7) * 8;
                *(uint4*)(dst + ((size_t)(b * Hc + h) * Tc + t) * Dc + d0) =
                    *(const uint4*)(SM + row * 128 + ((s ^ (row & 15)) * 8));
            }
        }
    }
}

// ---------------------------------------------------------------------------
// GEMM2: out = ab @ w_out^T, fp32 store. 64x128 tile (512 blocks = 2/CU).
// (round-1 config — measured good)
// ---------------------------------------------------------------------------
__global__ __launch_bounds__(256, 2) void gemm_out(
    const __hip_bfloat16* __restrict__ A,   // planar [bh][t][d]
    const __hip_bfloat16* __restrict__ Bm,  // 1024 x 1024
    float* __restrict__ Cout)
{
    __shared__ __align__(16) __hip_bfloat16 As[64 * 64];
    __shared__ __align__(16) __hip_bfloat16 Bs[128 * 64];

    const int tid  = threadIdx.x;
    const int lane = tid & 63, wave = tid >> 6;
    const int quad = lane >> 4, cidx = lane & 15;
    const int bm = blockIdx.x * 64, bn = blockIdx.y * 128;
    const int K = 1024;

    floatx4 acc[4][2] = {};

    for (int k0 = 0; k0 < K; k0 += 64) {
        int h = k0 >> 6;
#pragma unroll
        for (int it = 0; it < 2; ++it) {
            int idx = tid + it * 256;        // 0..511
            int r = idx >> 3, cs = idx & 7;
            int cg = cs ^ (r & 7);
            int m = bm + r;
            const __hip_bfloat16* src =
                A + ((size_t)((m >> 11) * 16 + h) * 2048 + (m & 2047)) * 64 + cg * 8;
            gload16(src, As + idx * 8);
        }
#pragma unroll
        for (int it = 0; it < 4; ++it) {
            int idx = tid + it * 256;        // 0..1023
            int r = idx >> 3, cs = idx & 7;
            int cg = cs ^ (r & 7);
            gload16(Bm + (size_t)(bn + r) * K + k0 + cg * 8, Bs + idx * 8);
        }
        __syncthreads();
#pragma unroll
        for (int ks = 0; ks < 2; ++ks) {
            bf16x8 af[4], bf[2];
#pragma unroll
            for (int mt = 0; mt < 4; ++mt) {
                int r = mt * 16 + cidx;
                af[mt] = *(const bf16x8*)(As + (r * 8 + ((ks * 4 + quad) ^ (r & 7))) * 8);
            }
#pragma unroll
            for (int nt = 0; nt < 2; ++nt) {
                int r = wave * 32 + nt * 16 + cidx;
                bf[nt] = *(const bf16x8*)(Bs + (r * 8 + ((ks * 4 + quad) ^ (r & 7))) * 8);
            }
#pragma unroll
            for (int mt = 0; mt < 4; ++mt)
#pragma unroll
                for (int nt = 0; nt < 2; ++nt)
                    acc[mt][nt] = __builtin_amdgcn_mfma_f32_16x16x32_bf16(
                        af[mt], bf[nt], acc[mt][nt], 0, 0, 0);
        }
        __syncthreads();
    }

#pragma unroll
    for (int mt = 0; mt < 4; ++mt)
#pragma unroll
        for (int nt = 0; nt < 2; ++nt) {
            int n = bn + wave * 32 + nt * 16 + cidx;
#pragma unroll
            for (int reg = 0; reg < 4; ++reg) {
                int m = bm + mt * 16 + quad * 4 + reg;
                Cout[(size_t)m * 1024 + n] = acc[mt][nt][reg];
            }
        }
}

// ---------------------------------------------------------------------------
// Causal MFMA flash attention v6: Q-split + 32q/wave A-fragment reuse.
// (unchanged from round 5 — measured good)
// ---------------------------------------------------------------------------
__global__ __launch_bounds__(256, 2) void attn_kernel(
    const __hip_bfloat16* __restrict__ qb,
    const __hip_bfloat16* __restrict__ kb,
    const __hip_bfloat16* __restrict__ vb,   // [bh][d][t]
    __hip_bfloat16* __restrict__ ob)         // planar [bh][t][d]
{
    __shared__ __align__(16) __hip_bfloat16 KB[2 * 128 * 64];  // K dbuf (32KB)
    __shared__ __align__(16) __hip_bfloat16 VB[2 * 64 * 128];  // V^T dbuf (32KB)

    const int tid  = threadIdx.x;
    const int lane = tid & 63, wave = tid >> 6;
    const int quad = lane >> 4, cidx = lane & 15;
    const int id = blockIdx.x;
    const int xcd = id & 7, s = id >> 3;      // s 0..63
    const int bh  = xcd * 4 + (s & 3);        // 4 bh planes per XCD
    const int m   = s >> 2;                   // 0..15
    const int qt  = (m < 8) ? (15 - m) : (m - 8);   // big blocks first
    const int qbase = qt * 128;
    const int ktmax = qt;
    const size_t plane = (size_t)bh * Tc * Dc;
    const __hip_bfloat16* Vp = vb + plane;
    const __hip_bfloat16* Kp = kb + plane;

    __hip_bfloat16* const Qs = KB + 128 * 64;   // Q staged in K buf1
    __hip_bfloat16* const Os = KB;              // O staged in K buf0

    // ---- prologue: stage Q -> Qs, K(0) -> KB[0], V(0) -> VB[0] ----
#pragma unroll
    for (int it = 0; it < 4; ++it) {
        int idx = tid + it * 256;               // 0..1023
        int r = idx >> 3, cg = (idx & 7) ^ (r & 7);
        gload16(qb + plane + (size_t)(qbase + r) * 64 + cg * 8, Qs + idx * 8);
    }
#pragma unroll
    for (int it = 0; it < 4; ++it) {
        int idx = tid + it * 256;
        int r = idx >> 3, cg = (idx & 7) ^ (r & 7);    // r = key row 0..127
        gload16(Kp + (size_t)r * 64 + cg * 8, KB + idx * 8);
    }
#pragma unroll
    for (int it = 0; it < 4; ++it) {
        int idx = tid + it * 256;
        int r = idx >> 4, c = (idx & 15) ^ (r & 15);   // r = d row 0..63
        gload16(Vp + (size_t)r * Tc + c * 8, VB + idx * 8);
    }
    __syncthreads();

    bf16x8 qf[2][2];
#pragma unroll
    for (int qb2 = 0; qb2 < 2; ++qb2)
#pragma unroll
        for (int ks = 0; ks < 2; ++ks) {
            int r = wave * 32 + qb2 * 16 + cidx;
            qf[qb2][ks] = *(const bf16x8*)(Qs + (r * 8 + ((ks * 4 + quad) ^ (r & 7))) * 8);
        }
    __syncthreads();   // qf in regs before kt=0 stages K(1) over Qs

    floatx4 oaccT[2][4] = {};        // [qb2][dt]; row=d, col=q
    floatx4 lpart[2] = {};           // 4 partial lsum chains per q-block
    const int q0 = qbase + wave * 32 + cidx;

    for (int kt = 0; kt <= ktmax; ++kt) {
        const __hip_bfloat16* Kc = KB + (kt & 1) * (128 * 64);
        const __hip_bfloat16* Vc = VB + (kt & 1) * (64 * 128);

        // stage next K/V tile into the other buffer (drains at end barrier)
        if (kt < ktmax) {
            __hip_bfloat16* Kn = KB + ((kt + 1) & 1) * (128 * 64);
            __hip_bfloat16* Vn = VB + ((kt + 1) & 1) * (64 * 128);
#pragma unroll
            for (int it = 0; it < 4; ++it) {
                int idx = tid + it * 256;
                int r = idx >> 3, cg = (idx & 7) ^ (r & 7);
                gload16(Kp + (size_t)((kt + 1) * 128 + r) * 64 + cg * 8, Kn + idx * 8);
            }
#pragma unroll
            for (int it = 0; it < 4; ++it) {
                int idx = tid + it * 256;
                int r = idx >> 4, c = (idx & 15) ^ (r & 15);
                gload16(Vp + (size_t)r * Tc + (kt + 1) * 128 + c * 8, Vn + idx * 8);
            }
        }

        // S^T = K Q^T : 128 keys x 2x16 q; each af read feeds both q-blocks
        floatx4 sacc[2][8] = {};
#pragma unroll
        for (int ks = 0; ks < 2; ++ks)
#pragma unroll
            for (int kb8 = 0; kb8 < 8; ++kb8) {
                int r = kb8 * 16 + cidx;
                bf16x8 af = *(const bf16x8*)(
                    Kc + (r * 8 + ((ks * 4 + quad) ^ (r & 7))) * 8);
                sacc[0][kb8] = __builtin_amdgcn_mfma_f32_16x16x32_bf16(
                    af, qf[0][ks], sacc[0][kb8], 0, 0, 0);
                sacc[1][kb8] = __builtin_amdgcn_mfma_f32_16x16x32_bf16(
                    af, qf[1][ks], sacc[1][kb8], 0, 0, 0);
            }

        // p = 2^s, causal mask on diagonal tile; pf register-direct
        const bool domask = (kt == ktmax);
        bf16x4 pf[2][8];
#pragma unroll
        for (int qb2 = 0; qb2 < 2; ++qb2) {
            const int q = q0 + qb2 * 16;
#pragma unroll
            for (int kb8 = 0; kb8 < 8; ++kb8)
#pragma unroll
                for (int reg = 0; reg < 4; ++reg) {
                    int key = kt * 128 + kb8 * 16 + quad * 4 + reg;
                    float p = __builtin_amdgcn_exp2f(sacc[qb2][kb8][reg]);
                    if (domask && key > q) p = 0.0f;
                    lpart[qb2][reg] += p;
                    __hip_bfloat16 hb = __float2bfloat16(p);
                    pf[qb2][kb8][reg] = *(const short*)&hb;
                }
        }

        // O^T += V^T P^T : each vtf read feeds both q-blocks
#pragma unroll
        for (int dt = 0; dt < 4; ++dt) {
            int d = dt * 16 + cidx;
#pragma unroll
            for (int c8 = 0; c8 < 8; ++c8) {
                int ch = c8 * 2 + (quad >> 1);
                bf16x4 vtf = *(const bf16x4*)(
                    Vc + (d * 16 + (ch ^ (d & 15))) * 8 + (quad & 1) * 4);
                oaccT[0][dt] = __builtin_amdgcn_mfma_f32_16x16x16bf16_1k(
                    vtf, pf[0][c8], oaccT[0][dt], 0, 0, 0);
                oaccT[1][dt] = __builtin_amdgcn_mfma_f32_16x16x16bf16_1k(
                    vtf, pf[1][c8], oaccT[1][dt], 0, 0, 0);
            }
        }

        __syncthreads();   // stage(kt+1) landed; buf[cur] reads done
    }

    // ---- epilogue: l reduce, normalize, transpose via Os, planar store ----
#pragma unroll
    for (int qb2 = 0; qb2 < 2; ++qb2) {
        float l = lpart[qb2][0] + lpart[qb2][1] + lpart[qb2][2] + lpart[qb2][3];
        l += __shfl_xor(l, 16);
        l += __shfl_xor(l, 32);
        float inv = 1.0f / l;
        int qq = wave * 32 + qb2 * 16 + cidx;
#pragma unroll
        for (int dt = 0; dt < 4; ++dt) {
            bf16x4 o4;
#pragma unroll
            for (int reg = 0; reg < 4; ++reg) {
                __hip_bfloat16 hb = __float2bfloat16(oaccT[qb2][dt][reg] * inv);
                o4[reg] = *(const short*)&hb;
            }
            int g = dt * 4 + quad;
            *(bf16x4*)(Os + qq * 64 + ((g ^ (qq & 12)) * 4)) = o4;
        }
    }
    __syncthreads();
    // cooperative planar store: 128 rows x 128B contiguous
#pragma unroll
    for (int i = 0; i < 4; ++i) {
        int c = tid + i * 256;               // 0..1023 16B chunks
        int row = c >> 3, cp = c & 7;
        *(uint4*)(ob + plane + (size_t)(qbase + row) * 64 + cp * 8) =
            *(const uint4*)(Os + row * 64 + ((cp * 2) ^ (row & 12)) * 4);
    }
}

// ---------------------------------------------------------------------------
extern "C" void kernel_launch(void* const* d_in, const int* in_sizes, int n_in,
                              void* d_out, int out_size, void* d_ws, size_t ws_size,
                              hipStream_t stream) {
    const float* xf = nullptr; const float* wqkvf = nullptr; const float* woutf = nullptr;
    for (int i = 0; i < n_in; ++i) {
        if      (in_sizes[i] == 2 * 2048 * 1024) xf    = (const float*)d_in[i];
        else if (in_sizes[i] == 3 * 1024 * 1024) wqkvf = (const float*)d_in[i];
        else if (in_sizes[i] == 1024 * 1024)     woutf = (const float*)d_in[i];
    }
    float* out = (float*)d_out;   // fp32 output (reference output dtype)

    char* ws = (char*)d_ws;
    const size_t MB = 1024 * 1024;
    __hip_bfloat16* qb    = (__hip_bfloat16*)(ws);
    __hip_bfloat16* kb    = (__hip_bfloat16*)(ws + 8  * MB);
    __hip_bfloat16* vb    = (__hip_bfloat16*)(ws + 16 * MB);   // transposed planes
    __hip_bfloat16* ab    = (__hip_bfloat16*)(ws + 24 * MB);   // planar [bh][t][d]
    float* cosT           = (float*)(ws + 32 * MB);
    float* sinT           = (float*)(ws + 32 * MB + 256 * 1024);
    __hip_bfloat16* xb    = (__hip_bfloat16*)(ws + 33 * MB);
    __hip_bfloat16* wqkvb = (__hip_bfloat16*)(ws + 41 * MB);
    __hip_bfloat16* woutb = (__hip_bfloat16*)(ws + 47 * MB);

    prep_kernel<<<dim3(8448), dim3(256), 0, stream>>>(
        xf, wqkvf, woutf, xb, wqkvb, woutb, cosT, sinT);

    // qkv projection + RoPE (+q pre-scale) + head scatter (v transposed via LDS)
    gemm_qkv<<<dim3(32, 24), dim3(256), 0, stream>>>(
        xb, wqkvb, qb, kb, vb, cosT, sinT, 1024);
    // causal flash attention -> ab planar (B,H,T,D) bf16
    attn_kernel<<<dim3(512), dim3(256), 0, stream>>>(qb, kb, vb, ab);
    // output projection (planar A), fp32 store to d_out
    gemm_out<<<dim3(64, 8), dim3(256), 0, stream>>>(ab, woutb, out);
}